// Round 2
// 105.688 us; speedup vs baseline: 1.0127x; 1.0127x over previous
//
#include <hip/hip_runtime.h>

typedef __attribute__((ext_vector_type(8))) short short8;
typedef __attribute__((ext_vector_type(4))) float f32x4;
typedef __attribute__((ext_vector_type(16))) float f32x16;
typedef __attribute__((ext_vector_type(2))) unsigned int u32x2;

#define NB 8
#define NC 256
#define NH 4
#define ND 64
#define NN 1024
#define OC3 768

__device__ __forceinline__ unsigned short f2bf(float f) {
  union { float f; unsigned int u; } a;
  a.f = f;
  unsigned int r = a.u + 0x7fffu + ((a.u >> 16) & 1u);
  return (unsigned short)(r >> 16);
}

// pack two fp32 -> bf16x2 (round-to-nearest): add 0x8000, perm high halves.
__device__ __forceinline__ unsigned int pkbf(float lo, float hi) {
  union { float f; unsigned int u; } a, b;
  a.f = lo; b.f = hi;
  return __builtin_amdgcn_perm(b.u + 0x8000u, a.u + 0x8000u, 0x07060302u);
}

// async global->LDS, 16 B per lane; lds dest is wave-uniform base + lane*16.
typedef const unsigned int __attribute__((address_space(1)))* gp_t;
typedef unsigned int __attribute__((address_space(3)))* lp_t;
__device__ __forceinline__ void glds16(const unsigned short* g, unsigned short* l) {
  __builtin_amdgcn_global_load_lds((gp_t)g, (lp_t)l, 16, 0, 0);
}

// ---------------------------------------------------------------------------
// fused transpose+cast for all three inputs (one launch):
//  z<8 : x batch z (256,1024) -> xs (1024,256)
//  z==8: Wp (256,768) -> WpT ; z==9: Wo (256,256) -> WoT
// ---------------------------------------------------------------------------
__global__ __launch_bounds__(256) void trans_all(
    const float* __restrict__ x, const float* __restrict__ Wp,
    const float* __restrict__ Wo, unsigned short* __restrict__ xs,
    unsigned short* __restrict__ WpT, unsigned short* __restrict__ WoT) {
  __shared__ float T[64][65];
  int z = blockIdx.z;
  const float* in; unsigned short* out; int R, S;
  if (z < 8) { in = x + (size_t)z * NC * NN; out = xs + (size_t)z * NC * NN; R = NC; S = NN; }
  else if (z == 8) { if (blockIdx.x >= 12) return; in = Wp; out = WpT; R = NC; S = OC3; }
  else { if (blockIdx.x >= 4) return; in = Wo; out = WoT; R = NC; S = NC; }
  int s0 = blockIdx.x * 64, r0 = blockIdx.y * 64;
  int t = threadIdx.x;
  {
    int ri = t >> 2, sb = t & 3;
    const float* p = in + (size_t)(r0 + ri) * S + s0 + sb * 16;
    float4 v0 = *(const float4*)(p);
    float4 v1 = *(const float4*)(p + 4);
    float4 v2 = *(const float4*)(p + 8);
    float4 v3 = *(const float4*)(p + 12);
    float vv[16] = {v0.x, v0.y, v0.z, v0.w, v1.x, v1.y, v1.z, v1.w,
                    v2.x, v2.y, v2.z, v2.w, v3.x, v3.y, v3.z, v3.w};
#pragma unroll
    for (int e = 0; e < 16; ++e) T[ri][sb * 16 + e] = vv[e];
  }
  __syncthreads();
  {
    int so = t >> 2, rb = t & 3;
    union { unsigned short us[16]; uint4 v[2]; } pk;
#pragma unroll
    for (int e = 0; e < 16; ++e) pk.us[e] = f2bf(T[rb * 16 + e][so]);
    uint4* dst = (uint4*)(out + (size_t)(s0 + so) * R + r0 + rb * 16);
    dst[0] = pk.v[0];
    dst[1] = pk.v[1];
  }
}

// ---------------------------------------------------------------------------
// GEMM1: qkv = xs(8192x256) @ Wp(256x768) + bp.  Writes Q/K/V in 32x32 MFMA
// FRAGMENT-MAJOR layout (per bh):
//  Q/K: frag[tile32(32)][dc(4)][lane64][e8] = X[tile32*32+(l&31)][dc*16+(l>>5)*8+e]
//       (Q pre-scaled by 0.125*log2(e))
//  V:   frag[(jt*2+ds)*4+kc][lane64][e8]    = V[jt*64+kc*16+(l>>5)*8+e][ds*32+(l&31)]
// Each region: 65536 shorts per bh (4 MB total each).
// ---------------------------------------------------------------------------
__global__ __launch_bounds__(256) void gemm_qkv(
    const unsigned short* __restrict__ xs, const unsigned short* __restrict__ WpT,
    const float* __restrict__ bp,
    unsigned short* __restrict__ Qf, unsigned short* __restrict__ Kf,
    unsigned short* __restrict__ Vf) {
  __shared__ __attribute__((aligned(16))) unsigned short Al[64 * 72];
  __shared__ __attribute__((aligned(16))) unsigned short Bl[64 * 72];
  int nt = blockIdx.x, mt = blockIdx.y;
  int t = threadIdx.x, w = t >> 6, l = t & 63, q = l >> 4, c = l & 15;
  f32x4 acc[4] = {{0, 0, 0, 0}, {0, 0, 0, 0}, {0, 0, 0, 0}, {0, 0, 0, 0}};
  const unsigned short* Arow = xs + (size_t)(mt * 64) * NC;
  const unsigned short* Brow = WpT + (size_t)(nt * 64) * NC;
  for (int k0 = 0; k0 < NC; k0 += 64) {
    __syncthreads();
#pragma unroll
    for (int it = 0; it < 2; ++it) {
      int u = t + it * 256;
      int row = u >> 3, kb = u & 7;
      *(uint4*)&Al[row * 72 + kb * 8] = *(const uint4*)(Arow + (size_t)row * NC + k0 + kb * 8);
      *(uint4*)&Bl[row * 72 + kb * 8] = *(const uint4*)(Brow + (size_t)row * NC + k0 + kb * 8);
    }
    __syncthreads();
#pragma unroll
    for (int ks = 0; ks < 2; ++ks) {
      short8 a = *(const short8*)&Al[(w * 16 + c) * 72 + ks * 32 + q * 8];
#pragma unroll
      for (int ct = 0; ct < 4; ++ct) {
        short8 b = *(const short8*)&Bl[(ct * 16 + c) * 72 + ks * 32 + q * 8];
        acc[ct] = __builtin_amdgcn_mfma_f32_16x16x32_bf16(a, b, acc[ct], 0, 0, 0);
      }
    }
  }
  int o0 = nt * 64;
  int h = o0 / 192, rem = o0 % 192;
  int b = mt >> 4, itl = mt & 15;
  int bh = b * NH + h;
  size_t rbase = (size_t)bh * 65536;
#pragma unroll
  for (int ct = 0; ct < 4; ++ct) {
    float bias = bp[o0 + ct * 16 + c];
#pragma unroll
    for (int r = 0; r < 4; ++r) acc[ct][r] += bias;
  }
  // acc[ct][r] = value at (row n = mt*64 + w*16 + q*4 + r, col d = ct*16 + c)
  if (rem < 128) {
    // Q or K: frag[tile32][dc=ct][l'][e] with
    //   l' = (c>>3)*32 + (w&1)*16 + q*4 + r,  e = c&7,  tile32 = itl*2 + (w>>1)
    unsigned short* dst = (rem == 0) ? Qf : Kf;
    float sc = (rem == 0) ? 0.18033688011112042f : 1.0f;  // 0.125*log2(e)
    int tile32 = itl * 2 + (w >> 1);
    int lpb = (c >> 3) * 32 + (w & 1) * 16 + q * 4;
    size_t tb = rbase + (size_t)tile32 * 2048 + (size_t)(c & 7);
#pragma unroll
    for (int ct = 0; ct < 4; ++ct)
#pragma unroll
      for (int r = 0; r < 4; ++r)
        dst[tb + (size_t)ct * 512 + (size_t)((lpb + r) * 8)] = f2bf(acc[ct][r] * sc);
  } else {
    // V: frag[(itl*2 + (ct>>1))*4 + w][l'][e] with
    //   l' = (q>>1)*32 + (ct&1)*16 + c,  e = (q&1)*4 + r  (4 contiguous shorts)
#pragma unroll
    for (int ct = 0; ct < 4; ++ct) {
      int f = itl * 8 + (ct >> 1) * 4 + w;
      int lp = (q >> 1) * 32 + (ct & 1) * 16 + c;
      size_t off = rbase + (size_t)f * 512 + (size_t)(lp * 8 + (q & 1) * 4);
      uint2 pk2 = {pkbf(acc[ct][0], acc[ct][1]), pkbf(acc[ct][2], acc[ct][3])};
      *(uint2*)&Vf[off] = pk2;
    }
  }
}

// ---------------------------------------------------------------------------
// attn v5: 32x32x16 MFMA.  Wave w: i-subtile isub=w>>1 (32 q-rows), j-half
// jh=w&1 (32 of the 64 j per tile).  S^T = mfma(K,Q): D col = i = l&31 is
// lane-local, rows j spread over 16 regs with 4*(l>>5) offset.  exp2 + lane
// row-sum; P -> PV A-fragment ENTIRELY IN REGISTERS via pkbf + 2x
// v_permlane32_swap per 16-j chunk (no P LDS round-trip).  K/V double-
// buffered in LDS via glds16, one barrier per j-tile (unchanged staging).
// Per wave per jt: 8 ds_read_b128 + 8 MFMA-32 (was 18 reads + 8 writes +
// 16 MFMA-16).  Wave-pair partial O / lsum combined once at the end via LDS.
// Grid 512 = 16 itiles x 32 bh, XCD-swizzled.
// ---------------------------------------------------------------------------
__global__ __launch_bounds__(256) void attn(
    const unsigned short* __restrict__ Qf, const unsigned short* __restrict__ Kf,
    const unsigned short* __restrict__ Vf, unsigned short* __restrict__ O) {
  __shared__ __attribute__((aligned(16))) unsigned short Kl[2][4096];
  __shared__ __attribute__((aligned(16))) unsigned short Vl[2][4096];
  int B = blockIdx.x;
  int bh = (B & 7) + 8 * ((B >> 3) & 3);  // same bh -> same XCD (blk%8 rr)
  int it = B >> 5;
  int t = threadIdx.x, w = t >> 6, l = t & 63;
  int jh = w & 1, isub = w >> 1;
  const unsigned short* Qt = Qf + (size_t)bh * 65536 + (size_t)(it * 2 + isub) * 2048;
  short8 bq[4];
#pragma unroll
  for (int dc = 0; dc < 4; ++dc) bq[dc] = *(const short8*)(Qt + dc * 512 + l * 8);
  const unsigned short* Kt = Kf + (size_t)bh * 65536;
  const unsigned short* Vt = Vf + (size_t)bh * 65536;

  // stage jt=0 -> buffer 0 (8 KB K + 8 KB V, 2 x 1KB chunks per wave each)
#pragma unroll
  for (int m = 0; m < 2; ++m) {
    int ch = (m * 4 + w) * 512;
    glds16(Kt + ch + l * 8, &Kl[0][ch]);
    glds16(Vt + ch + l * 8, &Vl[0][ch]);
  }

  float lsum = 0.f;
  f32x16 oacc0 = {0, 0, 0, 0, 0, 0, 0, 0, 0, 0, 0, 0, 0, 0, 0, 0};
  f32x16 oacc1 = {0, 0, 0, 0, 0, 0, 0, 0, 0, 0, 0, 0, 0, 0, 0, 0};
  int p = 0;
  for (int jt = 0; jt < 16; ++jt) {
    __syncthreads();  // staging of buf p complete; all waves done with p^1
    if (jt < 15) {
      const unsigned short* ksn = Kt + (size_t)(jt + 1) * 4096;
      const unsigned short* vsn = Vt + (size_t)(jt + 1) * 4096;
#pragma unroll
      for (int m = 0; m < 2; ++m) {
        int ch = (m * 4 + w) * 512;
        glds16(ksn + ch + l * 8, &Kl[p ^ 1][ch]);
        glds16(vsn + ch + l * 8, &Vl[p ^ 1][ch]);
      }
    }
    // S^T 32x32: lane l, reg rg = S[i = l&31][j = (rg&3)+8*(rg>>2)+4*(l>>5)]
    f32x16 sT = {0, 0, 0, 0, 0, 0, 0, 0, 0, 0, 0, 0, 0, 0, 0, 0};
#pragma unroll
    for (int dc = 0; dc < 4; ++dc) {
      short8 ka = *(const short8*)&Kl[p][(jh * 4 + dc) * 512 + l * 8];
      sT = __builtin_amdgcn_mfma_f32_32x32x16_bf16(ka, bq[dc], sT, 0, 0, 0);
    }
    float e_[16];
#pragma unroll
    for (int rg = 0; rg < 16; ++rg) {
      e_[rg] = __builtin_amdgcn_exp2f(sT[rg]);
      lsum += e_[rg];
    }
    // P -> A-frag in registers: per 16-j chunk kk, words
    //   w0/w2 = swap(pk(s0,s1), pk(s4,s5)),  w1/w3 = swap(pk(s2,s3), pk(s6,s7))
#pragma unroll
    for (int kk = 0; kk < 2; ++kk) {
      unsigned int x1 = pkbf(e_[kk * 8 + 0], e_[kk * 8 + 1]);
      unsigned int x2 = pkbf(e_[kk * 8 + 2], e_[kk * 8 + 3]);
      unsigned int y1 = pkbf(e_[kk * 8 + 4], e_[kk * 8 + 5]);
      unsigned int y2 = pkbf(e_[kk * 8 + 6], e_[kk * 8 + 7]);
      u32x2 r1 = __builtin_amdgcn_permlane32_swap(x1, y1, false, false);
      u32x2 r2 = __builtin_amdgcn_permlane32_swap(x2, y2, false, false);
      union { unsigned int u[4]; short8 s; } pa;
      pa.u[0] = r1.x; pa.u[1] = r2.x; pa.u[2] = r1.y; pa.u[3] = r2.y;
      int kc = jh * 2 + kk;
      short8 v0 = *(const short8*)&Vl[p][kc * 512 + l * 8];
      short8 v1 = *(const short8*)&Vl[p][(4 + kc) * 512 + l * 8];
      oacc0 = __builtin_amdgcn_mfma_f32_32x32x16_bf16(pa.s, v0, oacc0, 0, 0, 0);
      oacc1 = __builtin_amdgcn_mfma_f32_32x32x16_bf16(pa.s, v1, oacc1, 0, 0, 0);
    }
    p ^= 1;
  }
  // combine the two lane-halves' disjoint j coverage for row i = l&31
  lsum += __shfl_xor(lsum, 32);
  __syncthreads();  // all waves done with K/V buffers -> reuse as f32 scratch
  float* LF = (float*)&Kl[0][0];  // 4096 floats: wave-pair partial O
  float* LS = (float*)&Vl[0][0];  // 128 floats: wave-pair partial row-sums
  int pr = w >> 1;
  if (w & 1) {
#pragma unroll
    for (int rg = 0; rg < 16; ++rg) {
      LF[pr * 2048 + rg * 64 + l] = oacc0[rg];
      LF[pr * 2048 + 1024 + rg * 64 + l] = oacc1[rg];
    }
    LS[pr * 64 + l] = lsum;
  }
  __syncthreads();
  if (!(w & 1)) {
    lsum += LS[pr * 64 + l];
    float inv = 1.0f / lsum;  // row i = l&31
    int hi = l >> 5, cl = l & 31;
    int b = bh >> 2, h = bh & 3;
    int i0 = it * 64 + isub * 32;
#pragma unroll
    for (int rg = 0; rg < 16; ++rg) {
      int ri = (rg & 3) + 8 * (rg >> 2) + 4 * hi;
      float invr = __shfl(inv, ri, 64);
      float o0v = oacc0[rg] + LF[pr * 2048 + rg * 64 + l];
      float o1v = oacc1[rg] + LF[pr * 2048 + 1024 + rg * 64 + l];
      size_t base = ((size_t)b * NN + (i0 + ri)) * NC + h * ND + cl;
      O[base] = f2bf(o0v * invr);
      O[base + 32] = f2bf(o1v * invr);
    }
  }
}

// ---------------------------------------------------------------------------
// GEMM2: res = O @ Wo + bo; out = transpose(res) + x.
// ---------------------------------------------------------------------------
__global__ __launch_bounds__(256) void gemm_out(
    const unsigned short* __restrict__ O, const unsigned short* __restrict__ WoT,
    const float* __restrict__ bo, const float* __restrict__ x,
    float* __restrict__ out) {
  __shared__ __attribute__((aligned(16))) unsigned short Al[64 * 72];
  __shared__ __attribute__((aligned(16))) unsigned short Bl[64 * 72];
  __shared__ float Tl[64 * 65];
  int nt = blockIdx.x, mt = blockIdx.y;
  int t = threadIdx.x, w = t >> 6, l = t & 63, q = l >> 4, c = l & 15;
  f32x4 acc[4] = {{0, 0, 0, 0}, {0, 0, 0, 0}, {0, 0, 0, 0}, {0, 0, 0, 0}};
  const unsigned short* Arow = O + (size_t)(mt * 64) * NC;
  const unsigned short* Brow = WoT + (size_t)(nt * 64) * NC;
  for (int k0 = 0; k0 < NC; k0 += 64) {
    __syncthreads();
#pragma unroll
    for (int it = 0; it < 2; ++it) {
      int u = t + it * 256;
      int row = u >> 3, kb = u & 7;
      *(uint4*)&Al[row * 72 + kb * 8] = *(const uint4*)(Arow + (size_t)row * NC + k0 + kb * 8);
      *(uint4*)&Bl[row * 72 + kb * 8] = *(const uint4*)(Brow + (size_t)row * NC + k0 + kb * 8);
    }
    __syncthreads();
#pragma unroll
    for (int ks = 0; ks < 2; ++ks) {
      short8 a = *(const short8*)&Al[(w * 16 + c) * 72 + ks * 32 + q * 8];
#pragma unroll
      for (int ct = 0; ct < 4; ++ct) {
        short8 b = *(const short8*)&Bl[(ct * 16 + c) * 72 + ks * 32 + q * 8];
        acc[ct] = __builtin_amdgcn_mfma_f32_16x16x32_bf16(a, b, acc[ct], 0, 0, 0);
      }
    }
  }
#pragma unroll
  for (int ct = 0; ct < 4; ++ct) {
    float bias = bo[nt * 64 + ct * 16 + c];
#pragma unroll
    for (int r = 0; r < 4; ++r)
      Tl[(ct * 16 + c) * 65 + w * 16 + q * 4 + r] = acc[ct][r] + bias;
  }
  __syncthreads();
  int b = (mt * 64) >> 10, n0 = (mt * 64) & 1023;
  int cl = t >> 2, nb = t & 3;
  float v[16];
#pragma unroll
  for (int e = 0; e < 16; ++e) v[e] = Tl[cl * 65 + nb * 16 + e];
  size_t base = ((size_t)(b * NC + nt * 64 + cl)) * NN + n0 + nb * 16;
#pragma unroll
  for (int g = 0; g < 4; ++g) {
    float4 xv = *(const float4*)(x + base + g * 4);
    float4 ov;
    ov.x = v[g * 4 + 0] + xv.x;
    ov.y = v[g * 4 + 1] + xv.y;
    ov.z = v[g * 4 + 2] + xv.z;
    ov.w = v[g * 4 + 3] + xv.w;
    *(float4*)(out + base + g * 4) = ov;
  }
}

// ---------------------------------------------------------------------------
extern "C" void kernel_launch(void* const* d_in, const int* in_sizes, int n_in,
                              void* d_out, int out_size, void* d_ws, size_t ws_size,
                              hipStream_t stream) {
  const float* x = (const float*)d_in[0];
  const float* Wp = (const float*)d_in[1];
  const float* bp = (const float*)d_in[2];
  const float* Wo = (const float*)d_in[3];
  const float* bo = (const float*)d_in[4];
  float* out = (float*)d_out;
  char* ws = (char*)d_ws;
  unsigned short* xs  = (unsigned short*)(ws);             // 4 MB  (B,N,C) bf16
  unsigned short* WpT = (unsigned short*)(ws + 4194304);   // 384KB (768,256)
  unsigned short* WoT = (unsigned short*)(ws + 4587520);   // 128KB (256,256)
  unsigned short* Qfr = (unsigned short*)(ws + 4718592);   // 4 MB  frag-major
  unsigned short* Kfr = (unsigned short*)(ws + 8912896);   // 4 MB  frag-major
  unsigned short* Vfr = (unsigned short*)(ws + 13107200);  // 4 MB  frag-major
  unsigned short* Ob  = (unsigned short*)(ws + 17301504);  // 4 MB  (B,N,C)

  hipLaunchKernelGGL(trans_all, dim3(16, 4, 10), dim3(256), 0, stream,
                     x, Wp, Wo, xs, WpT, WoT);
  hipLaunchKernelGGL(gemm_qkv, dim3(12, 128), dim3(256), 0, stream, xs, WpT, bp,
                     Qfr, Kfr, Vfr);
  hipLaunchKernelGGL(attn, dim3(512), dim3(256), 0, stream, Qfr, Kfr, Vfr, Ob);
  hipLaunchKernelGGL(gemm_out, dim3(4, 128), dim3(256), 0, stream, Ob, WoT, bo, x, out);
}